// Round 2
// baseline (726.702 us; speedup 1.0000x reference)
//
#include <hip/hip_runtime.h>

typedef float  f32x4 __attribute__((ext_vector_type(4)));
typedef short  s16x8 __attribute__((ext_vector_type(8)));
typedef unsigned int u32x2 __attribute__((ext_vector_type(2)));
typedef unsigned int u32x4 __attribute__((ext_vector_type(4)));

#define NB     65536      // batch size
#define RPB    256        // rows per block
#define CR     32         // rows per chunk
#define NCH    8          // chunks per block
#define NBLK   256
#define NTHR   512
#define NSTEP  10
#define L2R    1e-4f
#define INVB   (1.0f/65536.0f)

// ---- LDS layout (bytes). Dynamic shared mem, 162816 total (<=160KiB). ----
// W arrays: [128][128] bf16, 16B-chunk XOR swizzle by (row&7).
#define OFF_W1H  0        // W[j][i] hi   (A for h-matvec: m=j,k=i)
#define OFF_W1L  32768    // W[j][i] lo
#define OFF_W2H  65536    // W^T[i][j] hi (A for v-matvec: m=i,k=j)
#define OFF_W2L  98304    // W^T[i][j] lo
#define OFF_VT   131072   // vt [32][128] bf16 swizzled (B operand, [n=r][k])
#define OFF_X    139264   // union: ht [32][128] swizzled (8192)  OR  phT [128][40] (10240)
#define OFF_VTT  151552   // vT [128][40] bf16 (B for G-GEMM, [n=i][k=r]), stride 40 shorts = 80B
#define OFF_HB   161792   // f32[128] hidden bias (reused as reduce scratch at end)
#define OFF_VB   162304   // f32[128] visible bias (reused as reduce scratch at end)
#define SMEM_SZ  162816

__device__ __forceinline__ unsigned short f2bf(float f){
  unsigned int u = __float_as_uint(f);
  u += 0x7fffu + ((u>>16)&1u);              // round-to-nearest-even
  return (unsigned short)(u>>16);
}
__device__ __forceinline__ float bf2f(unsigned short s){
  return __uint_as_float(((unsigned int)s)<<16);
}
__device__ __forceinline__ float sigm(float x){
  return __fdividef(1.0f, 1.0f + __expf(-x));
}
// 16B-chunk XOR swizzle for stride-256B rows (breaks the D=128 bank conflict, G4)
__device__ __forceinline__ int swz(int row, int byteInRow){
  return (row<<8) + (byteInRow ^ ((row&7)<<4));
}
__device__ __forceinline__ u32x2 pack4(unsigned short a, unsigned short b,
                                       unsigned short c, unsigned short d){
  u32x2 r; r[0] = (unsigned int)a | ((unsigned int)b<<16);
  r[1] = (unsigned int)c | ((unsigned int)d<<16); return r;
}

// Transposed matvec: C[m][n] over m = 128 dim (wave w owns m-tile w), n = 32 samples.
// A = Ahi/Alo [m][k] (hi/lo both accumulated), B = Bb [n][k]; K = 128 (4 MFMA K-steps).
// Frag layouts (gfx950 16x16x32 bf16): A lane: m=l&15, k=(l>>4)*8+t ; B lane: n=l&15, same k.
__device__ __forceinline__ void matvec128(const char* Ahi, const char* Alo, const char* Bb,
                                          int lane, int w, f32x4& c0, f32x4& c1){
  const int arow = (w<<4) + (lane&15);
  const int br0  = lane&15;
  const int br1  = 16 + (lane&15);
  const int koff = (lane>>4)<<4;            // byte offset of lane's k-group
  c0 = (f32x4){0.f,0.f,0.f,0.f};
  c1 = (f32x4){0.f,0.f,0.f,0.f};
  #pragma unroll
  for(int kk=0;kk<4;kk++){
    const int bIR = (kk<<6) + koff;         // kk*64 bytes + lane k-group
    s16x8 ah = *(const s16x8*)(Ahi + swz(arow,bIR));
    s16x8 al = *(const s16x8*)(Alo + swz(arow,bIR));
    s16x8 b0 = *(const s16x8*)(Bb  + swz(br0 ,bIR));
    s16x8 b1 = *(const s16x8*)(Bb  + swz(br1 ,bIR));
    c0 = __builtin_amdgcn_mfma_f32_16x16x32_bf16(ah,b0,c0,0,0,0);
    c0 = __builtin_amdgcn_mfma_f32_16x16x32_bf16(al,b0,c0,0,0,0);
    c1 = __builtin_amdgcn_mfma_f32_16x16x32_bf16(ah,b1,c1,0,0,0);
    c1 = __builtin_amdgcn_mfma_f32_16x16x32_bf16(al,b1,c1,0,0,0);
  }
}

extern "C" __global__ void __launch_bounds__(NTHR)
rbm_main(const float* __restrict__ batch,
         const float* __restrict__ wamp,
         const float* __restrict__ vbias,
         const float* __restrict__ hbias,
         const float* __restrict__ nh_g,
         const float* __restrict__ nv_g,
         float* __restrict__ out)
{
  extern __shared__ char smem[];
  char* W1H = smem+OFF_W1H;  char* W1L = smem+OFF_W1L;
  char* W2H = smem+OFF_W2H;  char* W2L = smem+OFF_W2L;
  char* VT  = smem+OFF_VT;   char* X   = smem+OFF_X;
  char* VTT = smem+OFF_VTT;
  float* hbL = (float*)(smem+OFF_HB);
  float* vbL = (float*)(smem+OFF_VB);

  const int t    = threadIdx.x;
  const int lane = t & 63;
  const int w    = t >> 6;

  // ---- one-time per block: split W into bf16 hi/lo, both orientations ----
  {
    const int j    = t>>2;              // 0..127
    const int iseg = (t&3)<<5;          // 0,32,64,96
    const float* src = wamp + j*128 + iseg;
    #pragma unroll
    for(int g=0; g<4; g++){
      f32x4 a0 = *(const f32x4*)(src + (g<<3));
      f32x4 a1 = *(const f32x4*)(src + (g<<3) + 4);
      float vv[8] = {a0[0],a0[1],a0[2],a0[3],a1[0],a1[1],a1[2],a1[3]};
      unsigned short hi[8], lo[8];
      #pragma unroll
      for(int e=0;e<8;e++){
        unsigned short h = f2bf(vv[e]);
        hi[e]=h; lo[e]=f2bf(vv[e] - bf2f(h));
      }
      u32x4 ph_, pl_;
      ph_[0]=hi[0]|((unsigned)hi[1]<<16); ph_[1]=hi[2]|((unsigned)hi[3]<<16);
      ph_[2]=hi[4]|((unsigned)hi[5]<<16); ph_[3]=hi[6]|((unsigned)hi[7]<<16);
      pl_[0]=lo[0]|((unsigned)lo[1]<<16); pl_[1]=lo[2]|((unsigned)lo[3]<<16);
      pl_[2]=lo[4]|((unsigned)lo[5]<<16); pl_[3]=lo[6]|((unsigned)lo[7]<<16);
      const int cbyte = (iseg + (g<<3))<<1;        // byte offset in row (mult of 16)
      *(u32x4*)(W1H + swz(j, cbyte)) = ph_;
      *(u32x4*)(W1L + swz(j, cbyte)) = pl_;
      #pragma unroll
      for(int e=0;e<8;e++){
        const int i = iseg+(g<<3)+e;               // transposed copy
        *(unsigned short*)(W2H + swz(i, j<<1)) = hi[e];
        *(unsigned short*)(W2L + swz(i, j<<1)) = lo[e];
      }
    }
    if(t<128){ hbL[t]=hbias[t]; vbL[t]=vbias[t]; }
  }

  f32x4 S[8];                                      // persistent outer-product accum
  #pragma unroll
  for(int n=0;n<8;n++) S[n]=(f32x4){0.f,0.f,0.f,0.f};
  float hbacc[4]={0,0,0,0};                        // phk - ph0 column partials
  float vbs[8]={0,0,0,0,0,0,0,0};                  // +vk partials (C mapping)
  float vbl[8]={0,0,0,0,0,0,0,0};                  // -v0 partials (load mapping)

  __syncthreads();

  const int j0 = (w<<4) + ((lane>>4)<<2);          // lane's 4 consecutive output rows
  const f32x4 hbv = *(const f32x4*)(hbL + j0);
  const f32x4 vbv = *(const f32x4*)(vbL + j0);
  const long blkrow = (long)blockIdx.x * RPB;

  for(int ch=0; ch<NCH; ch++){
    const int r0 = (int)blkrow + ch*CR;

    // ---- load v0 tile: vt (MFMA B layout) + vT (G-GEMM B layout) + vb(-) ----
    {
      const int lr = t>>4;                         // local row 0..31
      const int cb = (t&15)<<3;                    // 8 cols
      const float* src = batch + ((long)(r0+lr)<<7) + cb;
      f32x4 a0 = *(const f32x4*)(src);
      f32x4 a1 = *(const f32x4*)(src+4);
      float vv[8] = {a0[0],a0[1],a0[2],a0[3],a1[0],a1[1],a1[2],a1[3]};
      unsigned short bb[8];
      #pragma unroll
      for(int e=0;e<8;e++){ bb[e]=f2bf(vv[e]); vbl[e]-=vv[e]; }
      u32x4 pw;
      pw[0]=bb[0]|((unsigned)bb[1]<<16); pw[1]=bb[2]|((unsigned)bb[3]<<16);
      pw[2]=bb[4]|((unsigned)bb[5]<<16); pw[3]=bb[6]|((unsigned)bb[7]<<16);
      *(u32x4*)(VT + swz(lr, cb<<1)) = pw;
      #pragma unroll
      for(int e=0;e<8;e++)
        *(unsigned short*)(VTT + (cb+e)*80 + (lr<<1)) = bb[e];
    }
    __syncthreads();

    const int R0 = r0 + (lane&15);
    const int R1 = R0 + 16;

    // prefetch noise k=0 (h and v)
    f32x4 nh0 = *(const f32x4*)(nh_g + ((long)R0<<7) + j0);
    f32x4 nh1 = *(const f32x4*)(nh_g + ((long)R1<<7) + j0);
    f32x4 nv0 = *(const f32x4*)(nv_g + ((long)R0<<7) + j0);
    f32x4 nv1 = *(const f32x4*)(nv_g + ((long)R1<<7) + j0);

    // ---- positive phase: pre_h(v0) shared between ph0 and h0 sample ----
    f32x4 c0,c1;
    matvec128(W1H,W1L,VT,lane,w,c0,c1);
    float p0[4],p1[4];
    #pragma unroll
    for(int r2=0;r2<4;r2++){
      p0[r2]=sigm(c0[r2]+hbv[r2]);
      p1[r2]=sigm(c1[r2]+hbv[r2]);
      hbacc[r2]-=p0[r2]+p1[r2];
      // phT = -ph0 (negated so S accumulates neg-pos with adds only)
      *(unsigned short*)(X + (j0+r2)*80 + ((lane&15)<<1))      = f2bf(-p0[r2]);
      *(unsigned short*)(X + (j0+r2)*80 + ((16+(lane&15))<<1)) = f2bf(-p1[r2]);
    }
    __syncthreads();
    // G-pos: S -= ph0^T (x) v0   (A = phT [m=j][k=r], B = vT [n=i][k=r])
    {
      const int arow = (w<<4)+(lane&15);
      const int koff = (lane>>4)<<4;
      s16x8 a = *(const s16x8*)(X + arow*80 + koff);
      #pragma unroll
      for(int n=0;n<8;n++){
        s16x8 b = *(const s16x8*)(VTT + ((n<<4)+(lane&15))*80 + koff);
        S[n] = __builtin_amdgcn_mfma_f32_16x16x32_bf16(a,b,S[n],0,0,0);
      }
    }
    __syncthreads();
    // write h0 from held pre/noise (X now becomes ht)
    *(u32x2*)(X + swz(lane&15, j0<<1)) =
      pack4(nh0[0]<p0[0]?0x3f80:0, nh0[1]<p0[1]?0x3f80:0,
            nh0[2]<p0[2]?0x3f80:0, nh0[3]<p0[3]?0x3f80:0);
    *(u32x2*)(X + swz(16+(lane&15), j0<<1)) =
      pack4(nh1[0]<p1[0]?0x3f80:0, nh1[1]<p1[1]?0x3f80:0,
            nh1[2]<p1[2]?0x3f80:0, nh1[3]<p1[3]?0x3f80:0);
    __syncthreads();

    // ---- CD-k chain ----
    for(int k=0;k<NSTEP;k++){
      const bool pf = (k<NSTEP-1);
      const long kb = (long)(k+1)*NB;
      // prefetch nh[k+1] EARLY (regs dead: nh[k] consumed end of prev iter);
      // gives it ~2 matvecs + a barrier of latency cover (was ~1 matvec).
      if(pf){
        nh0 = *(const f32x4*)(nh_g + ((kb+R0)<<7) + j0);
        nh1 = *(const f32x4*)(nh_g + ((kb+R1)<<7) + j0);
      }
      // v update: pre_v = ht @ W + vb  (A = W2 [m=i][k=j], B = ht); consumes nv[k]
      matvec128(W2H,W2L,X,lane,w,c0,c1);
      unsigned short q0[4],q1[4];
      float vn0[4],vn1[4];
      #pragma unroll
      for(int r2=0;r2<4;r2++){
        float s0=sigm(c0[r2]+vbv[r2]);
        float s1=sigm(c1[r2]+vbv[r2]);
        vn0[r2]=(nv0[r2]<s0)?1.0f:0.0f;  q0[r2]=(nv0[r2]<s0)?0x3f80:0;
        vn1[r2]=(nv1[r2]<s1)?1.0f:0.0f;  q1[r2]=(nv1[r2]<s1)?0x3f80:0;
      }
      *(u32x2*)(VT + swz(lane&15,      j0<<1)) = pack4(q0[0],q0[1],q0[2],q0[3]);
      *(u32x2*)(VT + swz(16+(lane&15), j0<<1)) = pack4(q1[0],q1[1],q1[2],q1[3]);
      if(k==NSTEP-1){
        #pragma unroll
        for(int r2=0;r2<4;r2++){
          *(unsigned short*)(VTT + (j0+r2)*80 + ((lane&15)<<1))      = q0[r2];
          *(unsigned short*)(VTT + (j0+r2)*80 + ((16+(lane&15))<<1)) = q1[r2];
          vbs[r2]+=vn0[r2]; vbs[4+r2]+=vn1[r2];
        }
      }
      __syncthreads();
      if(pf){
        nv0 = *(const f32x4*)(nv_g + ((kb+R0)<<7) + j0);
        nv1 = *(const f32x4*)(nv_g + ((kb+R1)<<7) + j0);
        // h update: pre_h = vt @ W^T + hb; consumes nh[k+1] (prefetched at loop top)
        matvec128(W1H,W1L,VT,lane,w,c0,c1);
        #pragma unroll
        for(int r2=0;r2<4;r2++){
          float s0=sigm(c0[r2]+hbv[r2]);
          float s1=sigm(c1[r2]+hbv[r2]);
          q0[r2]=(nh0[r2]<s0)?0x3f80:0;
          q1[r2]=(nh1[r2]<s1)?0x3f80:0;
        }
        *(u32x2*)(X + swz(lane&15,      j0<<1)) = pack4(q0[0],q0[1],q0[2],q0[3]);
        *(u32x2*)(X + swz(16+(lane&15), j0<<1)) = pack4(q1[0],q1[1],q1[2],q1[3]);
        __syncthreads();
      }
    }

    // ---- negative phase: phk = sigmoid(vk @ W^T + hb) ----
    matvec128(W1H,W1L,VT,lane,w,c0,c1);
    #pragma unroll
    for(int r2=0;r2<4;r2++){
      p0[r2]=sigm(c0[r2]+hbv[r2]);
      p1[r2]=sigm(c1[r2]+hbv[r2]);
      hbacc[r2]+=p0[r2]+p1[r2];
      *(unsigned short*)(X + (j0+r2)*80 + ((lane&15)<<1))      = f2bf(p0[r2]);
      *(unsigned short*)(X + (j0+r2)*80 + ((16+(lane&15))<<1)) = f2bf(p1[r2]);
    }
    __syncthreads();
    // G-neg: S += phk^T (x) vk   (vT holds v10 from step 9)
    {
      const int arow = (w<<4)+(lane&15);
      const int koff = (lane>>4)<<4;
      s16x8 a = *(const s16x8*)(X + arow*80 + koff);
      #pragma unroll
      for(int n=0;n<8;n++){
        s16x8 b = *(const s16x8*)(VTT + ((n<<4)+(lane&15))*80 + koff);
        S[n] = __builtin_amdgcn_mfma_f32_16x16x32_bf16(a,b,S[n],0,0,0);
      }
    }
    __syncthreads();
  }

  // ---- write-out: S -> g_w_amp via atomics; biases via LDS reduce ----
  #pragma unroll
  for(int n=0;n<8;n++){
    #pragma unroll
    for(int r2=0;r2<4;r2++){
      const int e = ((w<<4)+((lane>>4)<<2)+r2)*128 + (n<<4)+(lane&15);
      atomicAdd(out + e, S[n][r2]*INVB);
    }
  }
  if(t<128){ hbL[t]=0.f; vbL[t]=0.f; }
  __syncthreads();
  #pragma unroll
  for(int r2=0;r2<4;r2++){
    atomicAdd(&hbL[j0+r2], hbacc[r2]);
    atomicAdd(&vbL[j0+r2], vbs[r2]+vbs[4+r2]);
  }
  {
    const int cb=(t&15)<<3;
    #pragma unroll
    for(int e=0;e<8;e++) atomicAdd(&vbL[cb+e], vbl[e]);
  }
  __syncthreads();
  if(t<128){
    atomicAdd(out+16384+t, vbL[t]*INVB);   // g_vb_amp
    atomicAdd(out+16512+t, hbL[t]*INVB);   // g_hb_amp
  }
}

// finalize: add L2 regularization, write phase outputs (runs after main, stream-ordered)
extern "C" __global__ void __launch_bounds__(256)
rbm_finalize(const float* __restrict__ wamp, const float* __restrict__ wphase,
             float* __restrict__ out)
{
  const int tid = blockIdx.x*256 + threadIdx.x;
  if(tid < 16384){
    out[tid]       += L2R * wamp[tid];     // g_w_amp  += L2*W (L1=0)
    out[16640+tid]  = L2R * wphase[tid];   // g_w_phase = L2*W_phase
  } else if(tid < 16640){
    out[16640+tid]  = 0.0f;                // g_vb_phase, g_hb_phase = 0
  }
}

extern "C" void kernel_launch(void* const* d_in, const int* in_sizes, int n_in,
                              void* d_out, int out_size, void* d_ws, size_t ws_size,
                              hipStream_t stream) {
  (void)in_sizes; (void)n_in; (void)d_ws; (void)ws_size; (void)out_size;
  const float* batch  = (const float*)d_in[0];
  const float* wamp   = (const float*)d_in[1];
  const float* vbias  = (const float*)d_in[2];
  const float* hbias  = (const float*)d_in[3];
  const float* wphase = (const float*)d_in[4];
  // d_in[5], d_in[6]: phase biases (unused — phase grads are L2-only / zero)
  const float* nh     = (const float*)d_in[7];
  const float* nv     = (const float*)d_in[8];
  float* out = (float*)d_out;

  hipFuncSetAttribute((const void*)rbm_main,
                      hipFuncAttributeMaxDynamicSharedMemorySize, SMEM_SZ);

  hipMemsetAsync(d_out, 0, (size_t)33280*sizeof(float), stream);
  rbm_main<<<dim3(NBLK), dim3(NTHR), SMEM_SZ, stream>>>(batch, wamp, vbias, hbias, nh, nv, out);
  rbm_finalize<<<dim3(65), dim3(256), 0, stream>>>(wamp, wphase, out);
}

// Round 4
// 698.639 us; speedup vs baseline: 1.0402x; 1.0402x over previous
//
#include <hip/hip_runtime.h>

typedef float  f32x4 __attribute__((ext_vector_type(4)));
typedef short  s16x8 __attribute__((ext_vector_type(8)));
typedef unsigned int u32x2 __attribute__((ext_vector_type(2)));
typedef unsigned int u32x4 __attribute__((ext_vector_type(4)));

#define NB     65536      // batch size
#define NBH    (65536*128)// element stride between noise k-steps
#define RPB    256        // rows per block
#define CR     32         // rows per chunk
#define NCH    8          // chunks per block
#define NBLK   256
#define NTHR   512
#define NSTEP  10
#define L2R    1e-4f
#define INVB   (1.0f/65536.0f)
#define WSPB   16640      // floats per block in ws: 16384 S + 128 vb + 128 hb
#define WS_NEED ((size_t)NBLK*WSPB*sizeof(float))

// ---- LDS layout (bytes). W regions are staging-only now (dead after prologue),
// kept at original offsets: occupancy is VGPR-capped at 8 waves/CU regardless.
#define OFF_W1H  0        // W[j][i] hi   (A for h-matvec: m=j,k=i)
#define OFF_W1L  32768    // W[j][i] lo
#define OFF_W2H  65536    // W^T[i][j] hi (A for v-matvec: m=i,k=j)
#define OFF_W2L  98304    // W^T[i][j] lo
#define OFF_VT   131072   // vt [32][128] bf16 swizzled (B operand, [n=r][k])
#define OFF_X    139264   // union: ht [32][128] swizzled (8192)  OR  phT [128][40] (10240)
#define OFF_VTT  151552   // vT [128][40] bf16 (B for G-GEMM, [n=i][k=r]), stride 80B
#define OFF_HB   161792   // f32[128] hidden bias (reused as reduce scratch at end)
#define OFF_VB   162304   // f32[128] visible bias (reused as reduce scratch at end)
#define SMEM_SZ  162816

__device__ __forceinline__ unsigned short f2bf(float f){
  unsigned int u = __float_as_uint(f);
  u += 0x7fffu + ((u>>16)&1u);              // round-to-nearest-even
  return (unsigned short)(u>>16);
}
__device__ __forceinline__ float bf2f(unsigned short s){
  return __uint_as_float(((unsigned int)s)<<16);
}
__device__ __forceinline__ float sigm(float x){
  return __fdividef(1.0f, 1.0f + __expf(-x));
}
// 16B-chunk XOR swizzle for stride-256B rows (breaks the D=128 bank conflict, G4)
__device__ __forceinline__ int swz(int row, int byteInRow){
  return (row<<8) + (byteInRow ^ ((row&7)<<4));
}
__device__ __forceinline__ u32x2 pack4(unsigned short a, unsigned short b,
                                       unsigned short c, unsigned short d){
  u32x2 r; r[0] = (unsigned int)a | ((unsigned int)b<<16);
  r[1] = (unsigned int)c | ((unsigned int)d<<16); return r;
}

#define MF(a,b,c) __builtin_amdgcn_mfma_f32_16x16x32_bf16(a,b,c,0,0,0)
// Transposed matvec with W fragments in registers. B rows br0=lane&15 (c0)
// and br0+16 (c1, = +4096B since row&7 preserved under +16). 8 ds_read_b128
// + 16 MFMA, zero address VALU (addresses precomputed in named VGPRs).
#define MATVEC(H0,H1,H2,H3,L0,L1,L2,L3,B0,B1,B2,B3)                      \
  do{ s16x8 b0_,b1_;                                                     \
    c0=(f32x4){0.f,0.f,0.f,0.f}; c1=(f32x4){0.f,0.f,0.f,0.f};           \
    b0_=*(const s16x8*)(B0); b1_=*(const s16x8*)((B0)+4096);             \
    c0=MF(H0,b0_,c0); c0=MF(L0,b0_,c0); c1=MF(H0,b1_,c1); c1=MF(L0,b1_,c1);\
    b0_=*(const s16x8*)(B1); b1_=*(const s16x8*)((B1)+4096);             \
    c0=MF(H1,b0_,c0); c0=MF(L1,b0_,c0); c1=MF(H1,b1_,c1); c1=MF(L1,b1_,c1);\
    b0_=*(const s16x8*)(B2); b1_=*(const s16x8*)((B2)+4096);             \
    c0=MF(H2,b0_,c0); c0=MF(L2,b0_,c0); c1=MF(H2,b1_,c1); c1=MF(L2,b1_,c1);\
    b0_=*(const s16x8*)(B3); b1_=*(const s16x8*)((B3)+4096);             \
    c0=MF(H3,b0_,c0); c0=MF(L3,b0_,c0); c1=MF(H3,b1_,c1); c1=MF(L3,b1_,c1);\
  }while(0)
#define MATVEC_H() MATVEC(W1H0,W1H1,W1H2,W1H3,W1L0,W1L1,W1L2,W1L3,bVT0,bVT1,bVT2,bVT3)
#define MATVEC_V() MATVEC(W2H0,W2H1,W2H2,W2H3,W2L0,W2L1,W2L2,W2L3,bX0,bX1,bX2,bX3)

template<bool USE_WS>
__global__ __launch_bounds__(NTHR, 2) void rbm_main_t(
         const float* __restrict__ batch,
         const float* __restrict__ wamp,
         const float* __restrict__ vbias,
         const float* __restrict__ hbias,
         const float* __restrict__ nh_g,
         const float* __restrict__ nv_g,
         float* __restrict__ sink)   // USE_WS: d_ws base; else: d_out
{
  extern __shared__ char smem[];
  char* W1Hp = smem+OFF_W1H;  char* W1Lp = smem+OFF_W1L;
  char* W2Hp = smem+OFF_W2H;  char* W2Lp = smem+OFF_W2L;
  char* VT  = smem+OFF_VT;   char* X   = smem+OFF_X;
  char* VTT = smem+OFF_VTT;
  float* hbL = (float*)(smem+OFF_HB);
  float* vbL = (float*)(smem+OFF_VB);

  const int t    = threadIdx.x;
  const int lane = t & 63;
  const int w    = t >> 6;

  // ---- one-time: split W into bf16 hi/lo, both orientations, in LDS ----
  {
    const int j    = t>>2;              // 0..127
    const int iseg = (t&3)<<5;          // 0,32,64,96
    const float* src = wamp + j*128 + iseg;
    #pragma unroll
    for(int g=0; g<4; g++){
      f32x4 a0 = *(const f32x4*)(src + (g<<3));
      f32x4 a1 = *(const f32x4*)(src + (g<<3) + 4);
      float vv[8] = {a0[0],a0[1],a0[2],a0[3],a1[0],a1[1],a1[2],a1[3]};
      unsigned short hi[8], lo[8];
      #pragma unroll
      for(int e=0;e<8;e++){
        unsigned short h = f2bf(vv[e]);
        hi[e]=h; lo[e]=f2bf(vv[e] - bf2f(h));
      }
      u32x4 ph_, pl_;
      ph_[0]=hi[0]|((unsigned)hi[1]<<16); ph_[1]=hi[2]|((unsigned)hi[3]<<16);
      ph_[2]=hi[4]|((unsigned)hi[5]<<16); ph_[3]=hi[6]|((unsigned)hi[7]<<16);
      pl_[0]=lo[0]|((unsigned)lo[1]<<16); pl_[1]=lo[2]|((unsigned)lo[3]<<16);
      pl_[2]=lo[4]|((unsigned)lo[5]<<16); pl_[3]=lo[6]|((unsigned)lo[7]<<16);
      const int cbyte = (iseg + (g<<3))<<1;
      *(u32x4*)(W1Hp + swz(j, cbyte)) = ph_;
      *(u32x4*)(W1Lp + swz(j, cbyte)) = pl_;
      #pragma unroll
      for(int e=0;e<8;e++){
        const int i = iseg+(g<<3)+e;               // transposed copy
        *(unsigned short*)(W2Hp + swz(i, j<<1)) = hi[e];
        *(unsigned short*)(W2Lp + swz(i, j<<1)) = lo[e];
      }
    }
    if(t<128){ hbL[t]=hbias[t]; vbL[t]=vbias[t]; }
  }
  __syncthreads();

  // ---- hoist W fragments into registers (A-operands for both directions) ----
  const int r15  = lane&15;
  const int koff = (lane>>4)<<4;            // byte offset of lane's k-group
  const int j0   = (w<<4) + ((lane>>4)<<2); // lane's 4 consecutive output rows
  s16x8 W1H0,W1H1,W1H2,W1H3, W1L0,W1L1,W1L2,W1L3;
  s16x8 W2H0,W2H1,W2H2,W2H3, W2L0,W2L1,W2L2,W2L3;
  {
    const int ar = (w<<4) + r15;
    W1H0=*(const s16x8*)(W1Hp+swz(ar,  0+koff)); W1L0=*(const s16x8*)(W1Lp+swz(ar,  0+koff));
    W1H1=*(const s16x8*)(W1Hp+swz(ar, 64+koff)); W1L1=*(const s16x8*)(W1Lp+swz(ar, 64+koff));
    W1H2=*(const s16x8*)(W1Hp+swz(ar,128+koff)); W1L2=*(const s16x8*)(W1Lp+swz(ar,128+koff));
    W1H3=*(const s16x8*)(W1Hp+swz(ar,192+koff)); W1L3=*(const s16x8*)(W1Lp+swz(ar,192+koff));
    W2H0=*(const s16x8*)(W2Hp+swz(ar,  0+koff)); W2L0=*(const s16x8*)(W2Lp+swz(ar,  0+koff));
    W2H1=*(const s16x8*)(W2Hp+swz(ar, 64+koff)); W2L1=*(const s16x8*)(W2Lp+swz(ar, 64+koff));
    W2H2=*(const s16x8*)(W2Hp+swz(ar,128+koff)); W2L2=*(const s16x8*)(W2Lp+swz(ar,128+koff));
    W2H3=*(const s16x8*)(W2Hp+swz(ar,192+koff)); W2L3=*(const s16x8*)(W2Lp+swz(ar,192+koff));
  }

  // ---- precomputed LDS addresses (named VGPRs; derived slots via offset:) ----
  char* aVT = VT + swz(r15, j0<<1);               // 8B vt write/read (+4096 = row+16)
  char* aX  = X  + swz(r15, j0<<1);               // 8B ht write
  const char* bVT0 = VT + swz(r15,   0+koff);     // B-frag reads (+4096 = c1 rows)
  const char* bVT1 = VT + swz(r15,  64+koff);
  const char* bVT2 = VT + swz(r15, 128+koff);
  const char* bVT3 = VT + swz(r15, 192+koff);
  const char* bX0  = X  + swz(r15,   0+koff);
  const char* bX1  = X  + swz(r15,  64+koff);
  const char* bX2  = X  + swz(r15, 128+koff);
  const char* bX3  = X  + swz(r15, 192+koff);
  const char* vttA = VTT + r15*80 + koff;         // G-GEMM B reads (+n*1280)
  const char* phA  = X   + ((w<<4)+r15)*80 + koff;// G-GEMM A reads
  char* vtW = VTT + j0*80 + (r15<<1);             // vk^T 2B writes (+r2*80, +32)
  char* phW = X   + j0*80 + (r15<<1);             // phT 2B writes

  f32x4 S[8];                                      // persistent outer-product accum
  #pragma unroll
  for(int n=0;n<8;n++) S[n]=(f32x4){0.f,0.f,0.f,0.f};
  float hbacc[4]={0,0,0,0};
  float vbs[8]={0,0,0,0,0,0,0,0};
  float vbl[8]={0,0,0,0,0,0,0,0};

  const f32x4 hbv = *(const f32x4*)(hbL + j0);
  const f32x4 vbv = *(const f32x4*)(vbL + j0);
  const long blkrow = (long)blockIdx.x * RPB;

  for(int ch=0; ch<NCH; ch++){
    const int r0 = (int)blkrow + ch*CR;

    // ---- load v0 tile into VT (+ vb(-) accum) ----
    {
      const int lr = t>>4;                         // local row 0..31
      const int cb = (t&15)<<3;                    // 8 cols
      const float* src = batch + ((long)(r0+lr)<<7) + cb;
      f32x4 a0 = *(const f32x4*)(src);
      f32x4 a1 = *(const f32x4*)(src+4);
      float vv[8] = {a0[0],a0[1],a0[2],a0[3],a1[0],a1[1],a1[2],a1[3]};
      unsigned short bb[8];
      #pragma unroll
      for(int e=0;e<8;e++){ bb[e]=f2bf(vv[e]); vbl[e]-=vv[e]; }
      u32x4 pw;
      pw[0]=bb[0]|((unsigned)bb[1]<<16); pw[1]=bb[2]|((unsigned)bb[3]<<16);
      pw[2]=bb[4]|((unsigned)bb[5]<<16); pw[3]=bb[6]|((unsigned)bb[7]<<16);
      *(u32x4*)(VT + swz(lr, cb<<1)) = pw;
    }
    __syncthreads();

    const int R0 = r0 + r15;
    // per-chunk noise pointers: k=0 direct; chain pointers start at k=1
    const float* nb_h0 = nh_g + ((long)R0<<7) + j0;
    const float* nb_h1 = nb_h0 + (16<<7);
    const float* nb_v0 = nv_g + ((long)R0<<7) + j0;
    const float* nb_v1 = nb_v0 + (16<<7);
    f32x4 nh0 = *(const f32x4*)nb_h0;
    f32x4 nh1 = *(const f32x4*)nb_h1;
    f32x4 nv0 = *(const f32x4*)nb_v0;
    f32x4 nv1 = *(const f32x4*)nb_v1;
    const float* pnh0 = nb_h0 + NBH;  const float* pnh1 = nb_h1 + NBH;
    const float* pnv0 = nb_v0 + NBH;  const float* pnv1 = nb_v1 + NBH;

    // ---- vT (G-GEMM B layout) fill from VT: conflict-free 2B stores ----
    {
      u32x2 a0 = *(const u32x2*)(aVT);
      u32x2 a1 = *(const u32x2*)(aVT+4096);
      *(unsigned short*)(vtW +   0) = (unsigned short)(a0[0]);
      *(unsigned short*)(vtW +  80) = (unsigned short)(a0[0]>>16);
      *(unsigned short*)(vtW + 160) = (unsigned short)(a0[1]);
      *(unsigned short*)(vtW + 240) = (unsigned short)(a0[1]>>16);
      *(unsigned short*)(vtW +  32) = (unsigned short)(a1[0]);
      *(unsigned short*)(vtW + 112) = (unsigned short)(a1[0]>>16);
      *(unsigned short*)(vtW + 192) = (unsigned short)(a1[1]);
      *(unsigned short*)(vtW + 272) = (unsigned short)(a1[1]>>16);
    }

    // ---- positive phase: pre_h(v0) shared between ph0 and h0 sample ----
    f32x4 c0,c1;
    MATVEC_H();
    float p0[4],p1[4];
    #pragma unroll
    for(int r2=0;r2<4;r2++){
      p0[r2]=sigm(c0[r2]+hbv[r2]);
      p1[r2]=sigm(c1[r2]+hbv[r2]);
      hbacc[r2]-=p0[r2]+p1[r2];
      // phT = -ph0 (negated so S accumulates neg-pos with adds only)
      *(unsigned short*)(phW + r2*80)      = f2bf(-p0[r2]);
      *(unsigned short*)(phW + r2*80 + 32) = f2bf(-p1[r2]);
    }
    __syncthreads();
    // G-pos: S -= ph0^T (x) v0
    {
      s16x8 a = *(const s16x8*)(phA);
      #pragma unroll
      for(int n=0;n<8;n++){
        s16x8 b = *(const s16x8*)(vttA + n*1280);
        S[n] = MF(a,b,S[n]);
      }
    }
    __syncthreads();
    // write h0 from held p/noise (X becomes ht)
    *(u32x2*)(aX)      = pack4(nh0[0]<p0[0]?0x3f80:0, nh0[1]<p0[1]?0x3f80:0,
                               nh0[2]<p0[2]?0x3f80:0, nh0[3]<p0[3]?0x3f80:0);
    *(u32x2*)(aX+4096) = pack4(nh1[0]<p1[0]?0x3f80:0, nh1[1]<p1[1]?0x3f80:0,
                               nh1[2]<p1[2]?0x3f80:0, nh1[3]<p1[3]?0x3f80:0);
    __syncthreads();

    // ---- CD-k chain ----
    for(int k=0;k<NSTEP;k++){
      const bool pf = (k<NSTEP-1);
      if(pf){                                    // prefetch nh[k+1] early
        nh0 = *(const f32x4*)pnh0;  pnh0 += NBH;
        nh1 = *(const f32x4*)pnh1;  pnh1 += NBH;
      }
      // v update: pre_v = ht @ W + vb; consumes nv[k]
      MATVEC_V();
      unsigned short q0[4],q1[4];
      #pragma unroll
      for(int r2=0;r2<4;r2++){
        // n < sigmoid(x)  <=>  fma(n, e^-x, n) < 1   (no v_rcp)
        float E0 = __expf(-(c0[r2]+vbv[r2]));
        float E1 = __expf(-(c1[r2]+vbv[r2]));
        q0[r2] = (__fmaf_rn(nv0[r2],E0,nv0[r2]) < 1.0f) ? 0x3f80 : 0;
        q1[r2] = (__fmaf_rn(nv1[r2],E1,nv1[r2]) < 1.0f) ? 0x3f80 : 0;
      }
      *(u32x2*)(aVT)      = pack4(q0[0],q0[1],q0[2],q0[3]);
      *(u32x2*)(aVT+4096) = pack4(q1[0],q1[1],q1[2],q1[3]);
      if(k==NSTEP-1){
        #pragma unroll
        for(int r2=0;r2<4;r2++){
          *(unsigned short*)(vtW + r2*80)      = q0[r2];
          *(unsigned short*)(vtW + r2*80 + 32) = q1[r2];
          vbs[r2]   += q0[r2] ? 1.0f : 0.0f;
          vbs[4+r2] += q1[r2] ? 1.0f : 0.0f;
        }
      }
      __syncthreads();
      if(pf){
        nv0 = *(const f32x4*)pnv0;  pnv0 += NBH;
        nv1 = *(const f32x4*)pnv1;  pnv1 += NBH;
        // h update: pre_h = vt @ W^T + hb; consumes nh[k+1]
        MATVEC_H();
        #pragma unroll
        for(int r2=0;r2<4;r2++){
          float E0 = __expf(-(c0[r2]+hbv[r2]));
          float E1 = __expf(-(c1[r2]+hbv[r2]));
          q0[r2] = (__fmaf_rn(nh0[r2],E0,nh0[r2]) < 1.0f) ? 0x3f80 : 0;
          q1[r2] = (__fmaf_rn(nh1[r2],E1,nh1[r2]) < 1.0f) ? 0x3f80 : 0;
        }
        *(u32x2*)(aX)      = pack4(q0[0],q0[1],q0[2],q0[3]);
        *(u32x2*)(aX+4096) = pack4(q1[0],q1[1],q1[2],q1[3]);
        __syncthreads();
      }
    }

    // ---- negative phase: phk = sigmoid(vk @ W^T + hb) ----
    MATVEC_H();
    #pragma unroll
    for(int r2=0;r2<4;r2++){
      p0[r2]=sigm(c0[r2]+hbv[r2]);
      p1[r2]=sigm(c1[r2]+hbv[r2]);
      hbacc[r2]+=p0[r2]+p1[r2];
      *(unsigned short*)(phW + r2*80)      = f2bf(p0[r2]);
      *(unsigned short*)(phW + r2*80 + 32) = f2bf(p1[r2]);
    }
    __syncthreads();
    // G-neg: S += phk^T (x) vk
    {
      s16x8 a = *(const s16x8*)(phA);
      #pragma unroll
      for(int n=0;n<8;n++){
        s16x8 b = *(const s16x8*)(vttA + n*1280);
        S[n] = MF(a,b,S[n]);
      }
    }
    __syncthreads();
  }

  // ---- write-out ----
  if(USE_WS){
    float* wsb = sink + (long)blockIdx.x*WSPB;
    #pragma unroll
    for(int n=0;n<8;n++){
      #pragma unroll
      for(int r2=0;r2<4;r2++)
        wsb[(j0+r2)*128 + (n<<4) + r15] = S[n][r2];
    }
    if(t<128){ hbL[t]=0.f; vbL[t]=0.f; }
    __syncthreads();
    #pragma unroll
    for(int r2=0;r2<4;r2++){
      atomicAdd(&hbL[j0+r2], hbacc[r2]);
      atomicAdd(&vbL[j0+r2], vbs[r2]+vbs[4+r2]);
    }
    {
      const int cb=(t&15)<<3;
      #pragma unroll
      for(int e=0;e<8;e++) atomicAdd(&vbL[cb+e], vbl[e]);
    }
    __syncthreads();
    if(t<128){
      wsb[16384+t] = vbL[t];   // vb partial (sign already folded)
      wsb[16512+t] = hbL[t];   // hb partial
    }
  } else {
    float* out = sink;
    #pragma unroll
    for(int n=0;n<8;n++){
      #pragma unroll
      for(int r2=0;r2<4;r2++)
        atomicAdd(out + (j0+r2)*128 + (n<<4)+r15, S[n][r2]*INVB);
    }
    if(t<128){ hbL[t]=0.f; vbL[t]=0.f; }
    __syncthreads();
    #pragma unroll
    for(int r2=0;r2<4;r2++){
      atomicAdd(&hbL[j0+r2], hbacc[r2]);
      atomicAdd(&vbL[j0+r2], vbs[r2]+vbs[4+r2]);
    }
    {
      const int cb=(t&15)<<3;
      #pragma unroll
      for(int e=0;e<8;e++) atomicAdd(&vbL[cb+e], vbl[e]);
    }
    __syncthreads();
    if(t<128){
      atomicAdd(out+16384+t, vbL[t]*INVB);
      atomicAdd(out+16512+t, hbL[t]*INVB);
    }
  }
}

// WS path: reduce 256 per-block partials + regularization + phase outputs.
extern "C" __global__ void __launch_bounds__(256)
rbm_reduce(const float* __restrict__ ws, const float* __restrict__ wamp,
           const float* __restrict__ wphase, float* __restrict__ out)
{
  const int tid = blockIdx.x*256 + threadIdx.x;
  if(tid < 16640){
    float s = 0.f;
    const float* p = ws + tid;
    #pragma unroll 4
    for(int b=0;b<NBLK;b++) s += p[(long)b*WSPB];
    if(tid<16384) out[tid] = s*INVB + L2R*wamp[tid];
    else          out[tid] = s*INVB;                  // vb, hb
  } else if(tid < 33024){
    out[tid] = L2R * wphase[tid-16640];               // g_w_phase
  } else if(tid < 33280){
    out[tid] = 0.0f;                                  // phase biases
  }
}

// Atomic-fallback finalize (adds L2 reg, writes phase outputs).
extern "C" __global__ void __launch_bounds__(256)
rbm_finalize(const float* __restrict__ wamp, const float* __restrict__ wphase,
             float* __restrict__ out)
{
  const int tid = blockIdx.x*256 + threadIdx.x;
  if(tid < 16384){
    out[tid]       += L2R * wamp[tid];
    out[16640+tid]  = L2R * wphase[tid];
  } else if(tid < 16640){
    out[16640+tid]  = 0.0f;
  }
}

extern "C" void kernel_launch(void* const* d_in, const int* in_sizes, int n_in,
                              void* d_out, int out_size, void* d_ws, size_t ws_size,
                              hipStream_t stream) {
  (void)in_sizes; (void)n_in; (void)out_size;
  const float* batch  = (const float*)d_in[0];
  const float* wamp   = (const float*)d_in[1];
  const float* vbias  = (const float*)d_in[2];
  const float* hbias  = (const float*)d_in[3];
  const float* wphase = (const float*)d_in[4];
  const float* nh     = (const float*)d_in[7];
  const float* nv     = (const float*)d_in[8];
  float* out = (float*)d_out;

  if(ws_size >= WS_NEED){
    hipFuncSetAttribute(reinterpret_cast<const void*>(&rbm_main_t<true>),
                        hipFuncAttributeMaxDynamicSharedMemorySize, SMEM_SZ);
    rbm_main_t<true><<<dim3(NBLK), dim3(NTHR), SMEM_SZ, stream>>>(
        batch, wamp, vbias, hbias, nh, nv, (float*)d_ws);
    rbm_reduce<<<dim3(130), dim3(256), 0, stream>>>((const float*)d_ws, wamp, wphase, out);
  } else {
    hipFuncSetAttribute(reinterpret_cast<const void*>(&rbm_main_t<false>),
                        hipFuncAttributeMaxDynamicSharedMemorySize, SMEM_SZ);
    hipMemsetAsync(d_out, 0, (size_t)33280*sizeof(float), stream);
    rbm_main_t<false><<<dim3(NBLK), dim3(NTHR), SMEM_SZ, stream>>>(
        batch, wamp, vbias, hbias, nh, nv, out);
    rbm_finalize<<<dim3(65), dim3(256), 0, stream>>>(wamp, wphase, out);
  }
}